// Round 1
// baseline (2348.234 us; speedup 1.0000x reference)
//
#include <hip/hip_runtime.h>
#include <cmath>
#include <cstddef>

// ACT cell (Adaptive Computation Time), fp32.
// B=4096, D=512, H=1024, O=512, MAX_ITER=10, EPS=0.01
//
// Decomposition:
//   xproj = x @ W_ih[:, :D].T + b_ih + b_hh          (once)
//   per step: s_new = tanh(xproj + flag*W_ih[:,D] + s @ W_hh.T)
//             h_n = sigmoid(s_new . W_halt + b_halt)  (per-row)
//             y  += p * (s_new @ W_ans.T + b_ans)
//             s_acc += p * s_new
//
// ws layout (floats): xproj[B*H] | s0[B*H] | s1[B*H] | wpk[H*D] | wcol[H]
//                     | h[B] r[B] R[B] N[B] stp[B] p[B]   (~50 MB)

#define MAX_ITER 10

// ---------------------------------------------------------------------------
// Generic NT GEMM:  C[M,N] = epi( A[M,K] * B[N,K]^T ),  row-major, K%BK==0.
// MODE 0: C = acc + e0[col] + e1[col]                        (xproj w/ biases)
// MODE 1: C = tanh(acc + e0[row*ldc+col] + flag*e1[col])     (recurrent step)
// MODE 2: C += e1[row] * (acc + e0[col])                     (y accumulate)
// 256 threads; wave-tiled 8x8 lane layout -> worst 2-way LDS aliasing (free).
// Register double-buffer: load tile t+1 to VGPRs while computing tile t.
// ---------------------------------------------------------------------------
template<int BM, int BN, int BK, int TM, int TN, int MODE>
__global__ __launch_bounds__(256)
void gemm_nt(const float* __restrict__ A, int lda,
             const float* __restrict__ Bm, int ldb,
             float* __restrict__ C, int ldc,
             int K,
             const float* __restrict__ e0,
             const float* __restrict__ e1,
             float flag)
{
    constexpr int PAD = 4;
    constexpr int NT_ = (BM * BN) / (TM * TN);   // must be 256
    constexpr int KF4 = BK / 4;
    constexpr int AF4 = (BM * BK) / (4 * NT_);
    constexpr int BF4 = (BN * BK) / (4 * NT_);
    constexpr int WM = 8 * TM, WN = 8 * TN;      // wave tile
    constexpr int WAVES_N = BN / WN;

    __shared__ __align__(16) float As[BK][BM + PAD];
    __shared__ __align__(16) float Bs[BK][BN + PAD];

    const int tid = threadIdx.x;
    const int m0 = blockIdx.x * BM;
    const int n0 = blockIdx.y * BN;
    const int wave = tid >> 6;
    const int lane = tid & 63;
    const int wm = wave / WAVES_N;
    const int wn = wave % WAVES_N;
    const int lm = lane >> 3;      // 0..7
    const int ln = lane & 7;       // 0..7
    const int rowb = wm * WM + lm * TM;   // row within tile
    const int colb = wn * WN + ln * TN;   // col within tile

    float acc[TM][TN];
#pragma unroll
    for (int i = 0; i < TM; i++)
#pragma unroll
        for (int j = 0; j < TN; j++) acc[i][j] = 0.f;

    float4 aR[AF4], bR[BF4];

    auto ldG = [&](int k0) {
#pragma unroll
        for (int i = 0; i < AF4; i++) {
            int idx = tid + i * NT_;
            int r = idx / KF4, c = idx % KF4;
            aR[i] = *reinterpret_cast<const float4*>(A + (size_t)(m0 + r) * lda + k0 + c * 4);
        }
#pragma unroll
        for (int i = 0; i < BF4; i++) {
            int idx = tid + i * NT_;
            int r = idx / KF4, c = idx % KF4;
            bR[i] = *reinterpret_cast<const float4*>(Bm + (size_t)(n0 + r) * ldb + k0 + c * 4);
        }
    };
    auto stS = [&]() {
#pragma unroll
        for (int i = 0; i < AF4; i++) {
            int idx = tid + i * NT_;
            int r = idx / KF4, c = idx % KF4;
            As[c * 4 + 0][r] = aR[i].x; As[c * 4 + 1][r] = aR[i].y;
            As[c * 4 + 2][r] = aR[i].z; As[c * 4 + 3][r] = aR[i].w;
        }
#pragma unroll
        for (int i = 0; i < BF4; i++) {
            int idx = tid + i * NT_;
            int r = idx / KF4, c = idx % KF4;
            Bs[c * 4 + 0][r] = bR[i].x; Bs[c * 4 + 1][r] = bR[i].y;
            Bs[c * 4 + 2][r] = bR[i].z; Bs[c * 4 + 3][r] = bR[i].w;
        }
    };

    ldG(0);
    stS();
    __syncthreads();

    const int NTILES = K / BK;
    for (int t = 0; t < NTILES; t++) {
        if (t + 1 < NTILES) ldG((t + 1) * BK);   // prefetch into regs
#pragma unroll
        for (int kk = 0; kk < BK; kk++) {
            float4 a4[TM / 4], b4[TN / 4];
#pragma unroll
            for (int i = 0; i < TM / 4; i++)
                a4[i] = *reinterpret_cast<const float4*>(&As[kk][rowb + i * 4]);
#pragma unroll
            for (int j = 0; j < TN / 4; j++)
                b4[j] = *reinterpret_cast<const float4*>(&Bs[kk][colb + j * 4]);
            const float* a = reinterpret_cast<const float*>(a4);
            const float* b = reinterpret_cast<const float*>(b4);
#pragma unroll
            for (int i = 0; i < TM; i++)
#pragma unroll
                for (int j = 0; j < TN; j++)
                    acc[i][j] = fmaf(a[i], b[j], acc[i][j]);
        }
        __syncthreads();
        if (t + 1 < NTILES) stS();
        __syncthreads();
    }

    // epilogue
#pragma unroll
    for (int i = 0; i < TM; i++) {
        const int row = m0 + rowb + i;
#pragma unroll
        for (int j4 = 0; j4 < TN / 4; j4++) {
            const int col = n0 + colb + j4 * 4;
            float4 v;
            v.x = acc[i][j4 * 4 + 0]; v.y = acc[i][j4 * 4 + 1];
            v.z = acc[i][j4 * 4 + 2]; v.w = acc[i][j4 * 4 + 3];
            float* cp = C + (size_t)row * ldc + col;
            if (MODE == 0) {
                float4 u = *reinterpret_cast<const float4*>(e0 + col);
                float4 w = *reinterpret_cast<const float4*>(e1 + col);
                v.x += u.x + w.x; v.y += u.y + w.y; v.z += u.z + w.z; v.w += u.w + w.w;
                *reinterpret_cast<float4*>(cp) = v;
            } else if (MODE == 1) {
                float4 xp = *reinterpret_cast<const float4*>(e0 + (size_t)row * ldc + col);
                float4 wc = *reinterpret_cast<const float4*>(e1 + col);
                v.x = tanhf(v.x + xp.x + flag * wc.x);
                v.y = tanhf(v.y + xp.y + flag * wc.y);
                v.z = tanhf(v.z + xp.z + flag * wc.z);
                v.w = tanhf(v.w + xp.w + flag * wc.w);
                *reinterpret_cast<float4*>(cp) = v;
            } else {
                const float pv = e1[row];
                float4 bb = *reinterpret_cast<const float4*>(e0 + col);
                float4 old = *reinterpret_cast<const float4*>(cp);
                v.x = fmaf(pv, v.x + bb.x, old.x);
                v.y = fmaf(pv, v.y + bb.y, old.y);
                v.z = fmaf(pv, v.z + bb.z, old.z);
                v.w = fmaf(pv, v.w + bb.w, old.w);
                *reinterpret_cast<float4*>(cp) = v;
            }
        }
    }
}

// ---------------------------------------------------------------------------
__global__ void init_kernel(float* __restrict__ out_zero, size_t nzero,
                            float* __restrict__ hA, float* __restrict__ rA,
                            float* __restrict__ RA, float* __restrict__ NA,
                            float* __restrict__ stA,
                            const float* __restrict__ prev_steps, int B)
{
    size_t i = (size_t)blockIdx.x * 256 + threadIdx.x;
    if (i < nzero) out_zero[i] = 0.f;
    if (i < (size_t)B) {
        hA[i] = 0.f; rA[i] = 1.f; RA[i] = 1.f; NA[i] = 0.f;
        stA[i] = prev_steps[i] + 1.f;
    }
}

// repack W_ih[H, D+1] (odd ld=513, float4-hostile) -> wpk[H,D] + wcol[H]
__global__ void repack_kernel(const float* __restrict__ Wih,
                              float* __restrict__ wpk, float* __restrict__ wcol,
                              int H, int D)
{
    size_t i = (size_t)blockIdx.x * 256 + threadIdx.x;
    if (i < (size_t)H * D) {
        int h = (int)(i / D), d = (int)(i % D);
        wpk[i] = Wih[(size_t)h * (D + 1) + d];
    }
    if (i < (size_t)H) wcol[i] = Wih[i * (size_t)(D + 1) + D];
}

// per-row halt: h_n = sigmoid(s_new . W_halt + b_halt); ACT state machine;
// also fuses s_acc += p * s_new (skipped when p==0, i.e. already-halted rows).
__global__ __launch_bounds__(256)
void halt_update(const float* __restrict__ s_new,
                 const float* __restrict__ Whalt, const float* __restrict__ bhalt,
                 float* __restrict__ hA, float* __restrict__ rA, float* __restrict__ RA,
                 float* __restrict__ NA, float* __restrict__ stA, float* __restrict__ pA,
                 float* __restrict__ s_acc, float n1, int H)
{
    const int b = blockIdx.x;
    const float4* row = reinterpret_cast<const float4*>(s_new + (size_t)b * H);
    const float4* wh = reinterpret_cast<const float4*>(Whalt);
    const int n4 = H / 4;
    float lsum = 0.f;
    for (int i = threadIdx.x; i < n4; i += 256) {
        float4 v = row[i], u = wh[i];
        lsum += v.x * u.x + v.y * u.y + v.z * u.z + v.w * u.w;
    }
#pragma unroll
    for (int off = 32; off > 0; off >>= 1) lsum += __shfl_down(lsum, off, 64);
    __shared__ float partial[4];
    __shared__ float psh;
    const int lane = threadIdx.x & 63, wv = threadIdx.x >> 6;
    if (lane == 0) partial[wv] = lsum;
    __syncthreads();
    if (threadIdx.x == 0) {
        float dot = partial[0] + partial[1] + partial[2] + partial[3] + bhalt[0];
        float h_n = 1.f / (1.f + expf(-dot));
        float hh = hA[b] + h_n;
        bool isN = hh >= 0.99f;                 // 1.0 - EPS
        float pv = isN ? rA[b] : h_n;
        float r_new = isN ? 0.f : 1.f - hh;
        if (!isN) { RA[b] = r_new; NA[b] = n1; stA[b] += 1.f; }
        hA[b] = hh; rA[b] = r_new; pA[b] = pv; psh = pv;
    }
    __syncthreads();
    const float pv = psh;
    if (pv != 0.f) {
        float4* sac = reinterpret_cast<float4*>(s_acc + (size_t)b * H);
        for (int i = threadIdx.x; i < n4; i += 256) {
            float4 v = row[i], o = sac[i];
            o.x = fmaf(pv, v.x, o.x); o.y = fmaf(pv, v.y, o.y);
            o.z = fmaf(pv, v.z, o.z); o.w = fmaf(pv, v.w, o.w);
            sac[i] = o;
        }
    }
}

// final remainder step: s_acc += r * s_new
__global__ void sacc_final(const float* __restrict__ s_new, const float* __restrict__ rA,
                           float* __restrict__ s_acc, int B, int H)
{
    size_t i = (size_t)blockIdx.x * 256 + threadIdx.x;   // float4 index
    size_t n4 = (size_t)B * H / 4;
    if (i < n4) {
        int b = (int)((i * 4) / H);
        float pv = rA[b];
        if (pv != 0.f) {
            float4 v = reinterpret_cast<const float4*>(s_new)[i];
            float4 o = reinterpret_cast<float4*>(s_acc)[i];
            o.x = fmaf(pv, v.x, o.x); o.y = fmaf(pv, v.y, o.y);
            o.z = fmaf(pv, v.z, o.z); o.w = fmaf(pv, v.w, o.w);
            reinterpret_cast<float4*>(s_acc)[i] = o;
        }
    }
}

__global__ void finalize_kernel(const float* __restrict__ pp, const float* __restrict__ RA,
                                const float* __restrict__ NA, const float* __restrict__ stA,
                                float* __restrict__ pon, float* __restrict__ stp, int B)
{
    int i = blockIdx.x * 256 + threadIdx.x;
    if (i < B) { pon[i] = pp[i] + RA[i] + NA[i]; stp[i] = stA[i]; }
}

// ---------------------------------------------------------------------------
extern "C" void kernel_launch(void* const* d_in, const int* in_sizes, int n_in,
                              void* d_out, int out_size, void* d_ws, size_t ws_size,
                              hipStream_t stream)
{
    const float* x     = (const float*)d_in[0];
    const float* ph    = (const float*)d_in[1];
    const float* pp    = (const float*)d_in[2];
    const float* ps    = (const float*)d_in[3];
    const float* Wih   = (const float*)d_in[4];
    const float* bih   = (const float*)d_in[5];
    const float* Whh   = (const float*)d_in[6];
    const float* bhh   = (const float*)d_in[7];
    const float* Whalt = (const float*)d_in[8];
    const float* bhalt = (const float*)d_in[9];
    const float* Wans  = (const float*)d_in[10];
    const float* bans  = (const float*)d_in[11];

    const int B = in_sizes[2];          // prev_ponder: B
    const int H = in_sizes[5];          // b_ih: H
    const int O = in_sizes[11];         // b_ans: O
    const int D = in_sizes[0] / B;      // x: B*D

    float* out_y   = (float*)d_out;
    float* out_sac = out_y + (size_t)B * O;
    float* out_pon = out_sac + (size_t)B * H;
    float* out_stp = out_pon + B;

    float* w = (float*)d_ws;
    float* xproj = w;  w += (size_t)B * H;
    float* s0    = w;  w += (size_t)B * H;
    float* s1    = w;  w += (size_t)B * H;
    float* wpk   = w;  w += (size_t)H * D;
    float* wcol  = w;  w += H;
    float* hA  = w; w += B;
    float* rA  = w; w += B;
    float* RA  = w; w += B;
    float* NA  = w; w += B;
    float* stA = w; w += B;
    float* pA  = w; w += B;

    const size_t nzero = (size_t)B * (O + H);   // y + s_acc regions of d_out
    init_kernel<<<(unsigned)((nzero + 255) / 256), 256, 0, stream>>>(
        out_y, nzero, hA, rA, RA, NA, stA, ps, B);
    repack_kernel<<<(unsigned)(((size_t)H * D + 255) / 256), 256, 0, stream>>>(
        Wih, wpk, wcol, H, D);

    // xproj = x @ wpk^T + b_ih + b_hh
    {
        dim3 g(B / 128, H / 128);
        gemm_nt<128, 128, 16, 8, 8, 0><<<g, 256, 0, stream>>>(
            x, D, wpk, D, xproj, H, D, bih, bhh, 0.f);
    }

    const float* scur = ph;
    float* snext = s0;
    for (int t = 0; t < MAX_ITER; t++) {
        const float flag = (t == 0) ? 1.f : 0.f;   // (MAX_ITER>1 so final flag=0)
        // s_new = tanh(xproj + flag*wcol + scur @ Whh^T)
        {
            dim3 g(B / 128, H / 128);
            gemm_nt<128, 128, 16, 8, 8, 1><<<g, 256, 0, stream>>>(
                scur, H, Whh, H, snext, H, H, xproj, wcol, flag);
        }
        const float* pptr;
        if (t < MAX_ITER - 1) {
            halt_update<<<B, 256, 0, stream>>>(
                snext, Whalt, bhalt, hA, rA, RA, NA, stA, pA,
                out_sac, (float)(t + 2), H);
            pptr = pA;
        } else {
            sacc_final<<<(unsigned)(((size_t)B * H / 4 + 255) / 256), 256, 0, stream>>>(
                snext, rA, out_sac, B, H);
            pptr = rA;
        }
        // y += p * (s_new @ Wans^T + b_ans)
        {
            dim3 g(B / 64, O / 128);
            gemm_nt<64, 128, 16, 4, 8, 2><<<g, 256, 0, stream>>>(
                snext, H, Wans, H, out_y, O, H, bans, pptr, 0.f);
        }
        scur = snext;
        snext = (snext == s0) ? s1 : s0;
    }

    finalize_kernel<<<(B + 255) / 256, 256, 0, stream>>>(
        pp, RA, NA, stA, out_pon, out_stp, B);
}

// Round 3
// 1484.624 us; speedup vs baseline: 1.5817x; 1.5817x over previous
//
#include <hip/hip_runtime.h>
#include <cmath>
#include <cstddef>

// ACT cell, B=4096 D=512 H=1024 O=512 MAX_ITER=10 EPS=0.01
//
// All GEMMs run on bf16 MFMA with split-3 fp32 emulation:
//   a = hi + lo (bf16 each);  a*b ~= hi*hi + hi*lo + lo*hi   (err ~2^-17)
// realized as a single GEMM over K' = 3K, where K-segment s selects
//   A from {hi, hi, lo}, B from {hi, lo, hi}.
// GEMM: 128x128 (or 128x64) tile, 4 waves, 16x16x32 bf16 MFMA, BK=64,
// global_load_lds(16B) with linear LDS dest + pre-swizzled global source,
// XOR-swizzled ds_read (conflict-free, rule-21 both-sides pattern).

#define MAX_ITER 10

typedef short bf16x8 __attribute__((ext_vector_type(8)));
typedef float f32x4  __attribute__((ext_vector_type(4)));

__device__ __forceinline__ ushort f2bf(float f) {
    unsigned u = __float_as_uint(f);
    u += 0x7fff + ((u >> 16) & 1);          // RNE
    return (ushort)(u >> 16);
}
__device__ __forceinline__ float bf2f(ushort b) {
    return __uint_as_float(((unsigned)b) << 16);
}
__device__ __forceinline__ void gld16(const void* g, void* l) {
    __builtin_amdgcn_global_load_lds(
        (const __attribute__((address_space(1))) void*)g,
        (__attribute__((address_space(3))) void*)l, 16, 0, 0);
}

// ---------------------------------------------------------------------------
// MODE 0: Cout = acc + e0[col] + e1[col]                    (xproj + biases)
// MODE 1: s = tanh(acc + e0[row*ldn+col] + flag*e1[col]); write split(s)
// MODE 2: Cout[row,col] += e1[row] * (acc + e0[col])        (y accumulate)
// ---------------------------------------------------------------------------
template<int BM, int BN, int MODE>
__global__ __launch_bounds__(256)
void mfma_gemm(const ushort* __restrict__ ahi, const ushort* __restrict__ alo, int lda,
               const ushort* __restrict__ bhi, const ushort* __restrict__ blo, int ldb,
               int tps,                       // K/64 tiles per segment
               float* __restrict__ Cout, int ldn,
               const float* __restrict__ e0,
               const float* __restrict__ e1,
               float flag,
               ushort* __restrict__ shiO, ushort* __restrict__ sloO)
{
    constexpr int FRM = BM / 32;             // 16-row fragments per wave
    constexpr int FRN = BN / 32;
    __shared__ __align__(16) ushort As[BM * 64];
    __shared__ __align__(16) ushort Bs[BN * 64];

    const int tid  = threadIdx.x;
    const int lane = tid & 63;
    const int wave = tid >> 6;
    const int lq   = lane & 15;
    const int kh   = lane >> 4;
    const int wr0  = (wave >> 1) * (BM / 2);
    const int wc0  = (wave & 1) * (BN / 2);
    const int m0   = blockIdx.x * BM;
    const int n0   = blockIdx.y * BN;

    f32x4 acc[FRM][FRN];
#pragma unroll
    for (int r = 0; r < FRM; ++r)
#pragma unroll
        for (int c = 0; c < FRN; ++c) acc[r][c] = (f32x4)0.f;

    const int steps = 3 * tps;
    for (int t = 0; t < steps; ++t) {
        const int seg = (t >= 2 * tps) ? 2 : ((t >= tps) ? 1 : 0);
        const int k0  = (t - seg * tps) * 64;
        const ushort* aS = (seg == 2) ? alo : ahi;
        const ushort* bS = (seg == 1) ? blo : bhi;

        // stage: linear LDS dest, inverse-swizzled global source
#pragma unroll
        for (int j = 0; j < BM / 32; ++j) {
            int c   = j * 256 + tid;
            int row = c >> 3;                       // 8 x 16B chunks per 128B row
            int kb  = ((c & 7) << 4) ^ ((row & 7) << 4);
            gld16(aS + (size_t)(m0 + row) * lda + k0 + (kb >> 1),
                  As + (size_t)(j * 256 + (tid & ~63)) * 8);
        }
#pragma unroll
        for (int j = 0; j < BN / 32; ++j) {
            int c   = j * 256 + tid;
            int row = c >> 3;
            int kb  = ((c & 7) << 4) ^ ((row & 7) << 4);
            gld16(bS + (size_t)(n0 + row) * ldb + k0 + (kb >> 1),
                  Bs + (size_t)(j * 256 + (tid & ~63)) * 8);
        }
        __syncthreads();

#pragma unroll
        for (int kt = 0; kt < 2; ++kt) {
            bf16x8 af[FRM], bfr[FRN];
#pragma unroll
            for (int r = 0; r < FRM; ++r) {
                int row = wr0 + r * 16 + lq;
                int kb  = (kt * 64 + kh * 16) ^ ((row & 7) << 4);
                af[r] = *reinterpret_cast<const bf16x8*>(&As[row * 64 + (kb >> 1)]);
            }
#pragma unroll
            for (int c = 0; c < FRN; ++c) {
                int row = wc0 + c * 16 + lq;
                int kb  = (kt * 64 + kh * 16) ^ ((row & 7) << 4);
                bfr[c] = *reinterpret_cast<const bf16x8*>(&Bs[row * 64 + (kb >> 1)]);
            }
#pragma unroll
            for (int r = 0; r < FRM; ++r)
#pragma unroll
                for (int c = 0; c < FRN; ++c)
                    acc[r][c] = __builtin_amdgcn_mfma_f32_16x16x32_bf16(
                        af[r], bfr[c], acc[r][c], 0, 0, 0);
        }
        __syncthreads();
    }

    // epilogue — C/D layout: col = lane&15, row = (lane>>4)*4 + q  [m89]
#pragma unroll
    for (int r = 0; r < FRM; ++r)
#pragma unroll
        for (int c = 0; c < FRN; ++c) {
            const size_t col = n0 + wc0 + c * 16 + lq;
#pragma unroll
            for (int q = 0; q < 4; ++q) {
                const size_t row = m0 + wr0 + r * 16 + kh * 4 + q;
                float v = acc[r][c][q];
                if constexpr (MODE == 0) {
                    v += e0[col] + e1[col];
                    Cout[row * ldn + col] = v;
                } else if constexpr (MODE == 1) {
                    v += e0[row * ldn + col];
                    if (flag != 0.f) v += flag * e1[col];
                    float s = tanhf(v);
                    ushort hb = f2bf(s);
                    ushort lb = f2bf(s - bf2f(hb));
                    shiO[row * ldn + col] = hb;
                    sloO[row * ldn + col] = lb;
                } else {
                    const float pv = e1[row];
                    float* cp = &Cout[row * ldn + col];
                    *cp = fmaf(pv, v + e0[col], *cp);
                }
            }
        }
}

// ---------------------------------------------------------------------------
__global__ void init_kernel(float* __restrict__ out_zero, size_t nzero,
                            float* __restrict__ hA, float* __restrict__ rA,
                            float* __restrict__ RA, float* __restrict__ NA,
                            float* __restrict__ stA,
                            const float* __restrict__ prev_steps, int B)
{
    size_t i = (size_t)blockIdx.x * 256 + threadIdx.x;
    if (i < nzero) out_zero[i] = 0.f;
    if (i < (size_t)B) {
        hA[i] = 0.f; rA[i] = 1.f; RA[i] = 1.f; NA[i] = 0.f;
        stA[i] = prev_steps[i] + 1.f;
    }
}

__global__ void split_f32(const float* __restrict__ src,
                          ushort* __restrict__ hi, ushort* __restrict__ lo, size_t n4)
{
    size_t i = (size_t)blockIdx.x * 256 + threadIdx.x;
    if (i < n4) {
        float4 v = reinterpret_cast<const float4*>(src)[i];
        ushort4 h, l;
        h.x = f2bf(v.x); l.x = f2bf(v.x - bf2f(h.x));
        h.y = f2bf(v.y); l.y = f2bf(v.y - bf2f(h.y));
        h.z = f2bf(v.z); l.z = f2bf(v.z - bf2f(h.z));
        h.w = f2bf(v.w); l.w = f2bf(v.w - bf2f(h.w));
        reinterpret_cast<ushort4*>(hi)[i] = h;
        reinterpret_cast<ushort4*>(lo)[i] = l;
    }
}

// W_ih[H, D+1] -> split [H,D] + wcol[H]
__global__ void wih_split(const float* __restrict__ Wih,
                          ushort* __restrict__ hi, ushort* __restrict__ lo,
                          float* __restrict__ wcol, int H, int D)
{
    size_t i = (size_t)blockIdx.x * 256 + threadIdx.x;
    if (i < (size_t)H * D) {
        int h = (int)(i / D), d = (int)(i % D);
        float v = Wih[(size_t)h * (D + 1) + d];
        ushort hb = f2bf(v);
        hi[i] = hb; lo[i] = f2bf(v - bf2f(hb));
    }
    if (i < (size_t)H) wcol[i] = Wih[i * (size_t)(D + 1) + D];
}

// per-row halt state machine + s_acc += p * s   (s reconstructed as hi+lo)
__global__ __launch_bounds__(256)
void halt_update(const ushort* __restrict__ shi, const ushort* __restrict__ slo,
                 const float* __restrict__ Whalt, const float* __restrict__ bhalt,
                 float* __restrict__ hA, float* __restrict__ rA, float* __restrict__ RA,
                 float* __restrict__ NA, float* __restrict__ stA, float* __restrict__ pA,
                 float* __restrict__ s_acc, float n1, int H, int isFinal)
{
    const int b = blockIdx.x;
    const int tid = threadIdx.x;
    const size_t base = (size_t)b * H;
    const int i = tid * 4;                     // H == 1024 == 256*4
    ushort4 h4 = *reinterpret_cast<const ushort4*>(shi + base + i);
    ushort4 l4 = *reinterpret_cast<const ushort4*>(slo + base + i);
    float s0 = bf2f(h4.x) + bf2f(l4.x);
    float s1 = bf2f(h4.y) + bf2f(l4.y);
    float s2 = bf2f(h4.z) + bf2f(l4.z);
    float s3 = bf2f(h4.w) + bf2f(l4.w);

    __shared__ float partial[4];
    __shared__ float psh;
    float4 w4 = *reinterpret_cast<const float4*>(Whalt + i);
    float lsum = s0 * w4.x + s1 * w4.y + s2 * w4.z + s3 * w4.w;
#pragma unroll
    for (int off = 32; off > 0; off >>= 1) lsum += __shfl_down(lsum, off, 64);
    if ((tid & 63) == 0) partial[tid >> 6] = lsum;
    __syncthreads();
    if (tid == 0) {
        float pv;
        if (isFinal) {
            pv = rA[b];
        } else {
            float dot = partial[0] + partial[1] + partial[2] + partial[3] + bhalt[0];
            float h_n = 1.f / (1.f + expf(-dot));
            float hh = hA[b] + h_n;
            bool isN = hh >= 0.99f;            // 1 - EPS
            pv = isN ? rA[b] : h_n;
            float r_new = isN ? 0.f : 1.f - hh;
            if (!isN) { RA[b] = r_new; NA[b] = n1; stA[b] += 1.f; }
            hA[b] = hh; rA[b] = r_new; pA[b] = pv;
        }
        psh = pv;
    }
    __syncthreads();
    const float pv = psh;
    if (pv != 0.f) {
        float4* sac = reinterpret_cast<float4*>(s_acc + base + i);
        float4 o = *sac;
        o.x = fmaf(pv, s0, o.x); o.y = fmaf(pv, s1, o.y);
        o.z = fmaf(pv, s2, o.z); o.w = fmaf(pv, s3, o.w);
        *sac = o;
    }
}

__global__ void finalize_kernel(const float* __restrict__ pp, const float* __restrict__ RA,
                                const float* __restrict__ NA, const float* __restrict__ stA,
                                float* __restrict__ pon, float* __restrict__ stp, int B)
{
    int i = blockIdx.x * 256 + threadIdx.x;
    if (i < B) { pon[i] = pp[i] + RA[i] + NA[i]; stp[i] = stA[i]; }
}

// ---------------------------------------------------------------------------
extern "C" void kernel_launch(void* const* d_in, const int* in_sizes, int n_in,
                              void* d_out, int out_size, void* d_ws, size_t ws_size,
                              hipStream_t stream)
{
    const float* x     = (const float*)d_in[0];
    const float* ph    = (const float*)d_in[1];
    const float* pp    = (const float*)d_in[2];
    const float* ps    = (const float*)d_in[3];
    const float* Wih   = (const float*)d_in[4];
    const float* bih   = (const float*)d_in[5];
    const float* Whh   = (const float*)d_in[6];
    const float* bhh   = (const float*)d_in[7];
    const float* Whalt = (const float*)d_in[8];
    const float* bhalt = (const float*)d_in[9];
    const float* Wans  = (const float*)d_in[10];
    const float* bans  = (const float*)d_in[11];

    const int B = in_sizes[2];
    const int H = in_sizes[5];
    const int O = in_sizes[11];
    const int D = in_sizes[0] / B;

    float* out_y   = (float*)d_out;
    float* out_sac = out_y + (size_t)B * O;
    float* out_pon = out_sac + (size_t)B * H;
    float* out_stp = out_pon + B;

    // workspace layout (16B-aligned chunks)
    char* w = (char*)d_ws;
    float* xproj = (float*)w;  w += (size_t)B * H * 4;
    ushort* shi[2], *slo[2];
    shi[0] = (ushort*)w; w += (size_t)B * H * 2;
    slo[0] = (ushort*)w; w += (size_t)B * H * 2;
    shi[1] = (ushort*)w; w += (size_t)B * H * 2;
    slo[1] = (ushort*)w; w += (size_t)B * H * 2;
    ushort* whhhi = (ushort*)w; w += (size_t)H * H * 2;
    ushort* whhlo = (ushort*)w; w += (size_t)H * H * 2;
    ushort* wanshi = (ushort*)w; w += (size_t)O * H * 2;
    ushort* wanslo = (ushort*)w; w += (size_t)O * H * 2;
    ushort* wihhi = (ushort*)w; w += (size_t)H * D * 2;
    ushort* wihlo = (ushort*)w; w += (size_t)H * D * 2;
    float* wcol = (float*)w; w += (size_t)H * 4;
    float* hA  = (float*)w; w += (size_t)B * 4;
    float* rA  = (float*)w; w += (size_t)B * 4;
    float* RA  = (float*)w; w += (size_t)B * 4;
    float* NA  = (float*)w; w += (size_t)B * 4;
    float* stA = (float*)w; w += (size_t)B * 4;
    float* pA  = (float*)w; w += (size_t)B * 4;

    // x split buffers alias s[1] ping-pong (dead before s[1] first written):
    // x-split is consumed only by the xproj GEMM, which completes before the
    // t=0 recurrent GEMM writes shi[1]/slo[1].
    ushort* xhi = shi[1];
    ushort* xlo = slo[1];

    const size_t nzero = (size_t)B * (O + H);
    init_kernel<<<(unsigned)((nzero + 255) / 256), 256, 0, stream>>>(
        out_y, nzero, hA, rA, RA, NA, stA, ps, B);

    split_f32<<<(unsigned)(((size_t)B * D / 4 + 255) / 256), 256, 0, stream>>>(x, xhi, xlo, (size_t)B * D / 4);
    split_f32<<<(unsigned)(((size_t)B * H / 4 + 255) / 256), 256, 0, stream>>>(ph, shi[0], slo[0], (size_t)B * H / 4);
    split_f32<<<(unsigned)(((size_t)H * H / 4 + 255) / 256), 256, 0, stream>>>(Whh, whhhi, whhlo, (size_t)H * H / 4);
    split_f32<<<(unsigned)(((size_t)O * H / 4 + 255) / 256), 256, 0, stream>>>(Wans, wanshi, wanslo, (size_t)O * H / 4);
    wih_split<<<(unsigned)(((size_t)H * D + 255) / 256), 256, 0, stream>>>(Wih, wihhi, wihlo, wcol, H, D);

    // xproj = x @ W_ih[:, :D]^T + b_ih + b_hh
    {
        dim3 g(B / 128, H / 128);
        mfma_gemm<128, 128, 0><<<g, 256, 0, stream>>>(
            xhi, xlo, D, wihhi, wihlo, D, D / 64,
            xproj, H, bih, bhh, 0.f, nullptr, nullptr);
    }

    int cur = 0;
    for (int t = 0; t < MAX_ITER; t++) {
        const int nxt = cur ^ 1;
        const float flag = (t == 0) ? 1.f : 0.f;
        // s_new = tanh(xproj + flag*wcol + s @ Whh^T)  -> split into shi/slo[nxt]
        {
            dim3 g(B / 128, H / 128);
            mfma_gemm<128, 128, 1><<<g, 256, 0, stream>>>(
                shi[cur], slo[cur], H, whhhi, whhlo, H, H / 64,
                nullptr, H, xproj, wcol, flag, shi[nxt], slo[nxt]);
        }
        const int isFinal = (t == MAX_ITER - 1);
        halt_update<<<B, 256, 0, stream>>>(
            shi[nxt], slo[nxt], Whalt, bhalt, hA, rA, RA, NA, stA, pA,
            out_sac, (float)(t + 2), H, isFinal);
        // y += p * (s_new @ Wans^T + b_ans)
        {
            dim3 g(B / 128, O / 64);
            mfma_gemm<128, 64, 2><<<g, 256, 0, stream>>>(
                shi[nxt], slo[nxt], H, wanshi, wanslo, H, H / 64,
                out_y, O, bans, isFinal ? rA : pA, 0.f, nullptr, nullptr);
        }
        cur = nxt;
    }

    finalize_kernel<<<(B + 255) / 256, 256, 0, stream>>>(
        pp, RA, NA, stA, out_pon, out_stp, B);
}

// Round 7
// 992.382 us; speedup vs baseline: 2.3663x; 1.4960x over previous
//
#include <hip/hip_runtime.h>
#include <cmath>
#include <cstddef>

// ACT cell, B=4096 D=512 H=1024 O=512 MAX_ITER=10 EPS=0.01
//
// GEMMs: bf16 MFMA split-3 fp32 emulation (hi*hi + hi*lo + lo*hi), K'=3K.
// Round 4: 64-row tiles (grid 512 = 2 blocks/CU, 2 waves/SIMD) + LDS
// double-buffer with stage-ahead (issue t+1 loads before computing t,
// ONE barrier per K-tile) — loads in flight under compute.

#define MAX_ITER 10

typedef short bf16x8 __attribute__((ext_vector_type(8)));
typedef float f32x4  __attribute__((ext_vector_type(4)));

__device__ __forceinline__ ushort f2bf(float f) {
    unsigned u = __float_as_uint(f);
    u += 0x7fff + ((u >> 16) & 1);          // RNE
    return (ushort)(u >> 16);
}
__device__ __forceinline__ float bf2f(ushort b) {
    return __uint_as_float(((unsigned)b) << 16);
}
__device__ __forceinline__ void gld16(const void* g, void* l) {
    __builtin_amdgcn_global_load_lds(
        (const __attribute__((address_space(1))) void*)g,
        (__attribute__((address_space(3))) void*)l, 16, 0, 0);
}

// ---------------------------------------------------------------------------
// MODE 0: Cout = acc + e0[col] + e1[col]                    (xproj + biases)
// MODE 1: s = tanh(acc + e0[row*ldn+col] + flag*e1[col]); write split(s)
// MODE 2: Cout[row,col] += e1[row] * (acc + e0[col])        (y accumulate)
// 256 threads, 4 waves in 2x2; wave tile (BM/2)x(BN/2).
// ---------------------------------------------------------------------------
template<int BM, int BN, int MODE>
__global__ __launch_bounds__(256)
void mfma_gemm(const ushort* __restrict__ ahi, const ushort* __restrict__ alo, int lda,
               const ushort* __restrict__ bhi, const ushort* __restrict__ blo, int ldb,
               int tps,                       // K/64 tiles per segment
               float* __restrict__ Cout, int ldn,
               const float* __restrict__ e0,
               const float* __restrict__ e1,
               float flag,
               ushort* __restrict__ shiO, ushort* __restrict__ sloO)
{
    constexpr int FRM = BM / 32;             // 16-row fragments per wave
    constexpr int FRN = BN / 32;
    __shared__ __align__(16) ushort As[2][BM * 64];
    __shared__ __align__(16) ushort Bs[2][BN * 64];

    const int tid  = threadIdx.x;
    const int lane = tid & 63;
    const int wave = tid >> 6;
    const int lq   = lane & 15;
    const int kh   = lane >> 4;
    const int wr0  = (wave >> 1) * (BM / 2);
    const int wc0  = (wave & 1) * (BN / 2);
    const int m0   = blockIdx.x * BM;
    const int n0   = blockIdx.y * BN;

    f32x4 acc[FRM][FRN];
#pragma unroll
    for (int r = 0; r < FRM; ++r)
#pragma unroll
        for (int c = 0; c < FRN; ++c) acc[r][c] = (f32x4)0.f;

    const int steps = 3 * tps;

    auto stage = [&](int buf, int t) {
        const int seg = (t >= 2 * tps) ? 2 : ((t >= tps) ? 1 : 0);
        const int k0  = (t - seg * tps) * 64;
        const ushort* aS = (seg == 2) ? alo : ahi;
        const ushort* bS = (seg == 1) ? blo : bhi;
#pragma unroll
        for (int j = 0; j < BM / 32; ++j) {
            int c   = j * 256 + tid;
            int row = c >> 3;                       // 8 x 16B chunks per 128B row
            int kb  = ((c & 7) << 4) ^ ((row & 7) << 4);
            gld16(aS + (size_t)(m0 + row) * lda + k0 + (kb >> 1),
                  &As[buf][(size_t)(j * 256 + (tid & ~63)) * 8]);
        }
#pragma unroll
        for (int j = 0; j < BN / 32; ++j) {
            int c   = j * 256 + tid;
            int row = c >> 3;
            int kb  = ((c & 7) << 4) ^ ((row & 7) << 4);
            gld16(bS + (size_t)(n0 + row) * ldb + k0 + (kb >> 1),
                  &Bs[buf][(size_t)(j * 256 + (tid & ~63)) * 8]);
        }
    };

    stage(0, 0);
    __syncthreads();                 // prologue: tile 0 resident

    int cur = 0;
    for (int t = 0; t < steps; ++t) {
        if (t + 1 < steps) stage(cur ^ 1, t + 1);   // prefetch in flight
        const ushort* Ab = As[cur];
        const ushort* Bb = Bs[cur];
#pragma unroll
        for (int kt = 0; kt < 2; ++kt) {
            bf16x8 af[FRM], bfr[FRN];
#pragma unroll
            for (int r = 0; r < FRM; ++r) {
                int row = wr0 + r * 16 + lq;
                int kb  = (kt * 64 + kh * 16) ^ ((row & 7) << 4);
                af[r] = *reinterpret_cast<const bf16x8*>(&Ab[row * 64 + (kb >> 1)]);
            }
#pragma unroll
            for (int c = 0; c < FRN; ++c) {
                int row = wc0 + c * 16 + lq;
                int kb  = (kt * 64 + kh * 16) ^ ((row & 7) << 4);
                bfr[c] = *reinterpret_cast<const bf16x8*>(&Bb[row * 64 + (kb >> 1)]);
            }
#pragma unroll
            for (int r = 0; r < FRM; ++r)
#pragma unroll
                for (int c = 0; c < FRN; ++c)
                    acc[r][c] = __builtin_amdgcn_mfma_f32_16x16x32_bf16(
                        af[r], bfr[c], acc[r][c], 0, 0, 0);
        }
        __syncthreads();     // drains prefetch (vmcnt0) + all reads of buf[cur]
        cur ^= 1;
    }

    // epilogue — C/D layout: col = lane&15, row = (lane>>4)*4 + q  [m89]
#pragma unroll
    for (int r = 0; r < FRM; ++r)
#pragma unroll
        for (int c = 0; c < FRN; ++c) {
            const size_t col = n0 + wc0 + c * 16 + lq;
#pragma unroll
            for (int q = 0; q < 4; ++q) {
                const size_t row = m0 + wr0 + r * 16 + kh * 4 + q;
                float v = acc[r][c][q];
                if constexpr (MODE == 0) {
                    v += e0[col] + e1[col];
                    Cout[row * ldn + col] = v;
                } else if constexpr (MODE == 1) {
                    v += e0[row * ldn + col];
                    if (flag != 0.f) v += flag * e1[col];
                    float s = tanhf(v);
                    ushort hb = f2bf(s);
                    ushort lb = f2bf(s - bf2f(hb));
                    shiO[row * ldn + col] = hb;
                    sloO[row * ldn + col] = lb;
                } else {
                    const float pv = e1[row];
                    float* cp = &Cout[row * ldn + col];
                    *cp = fmaf(pv, v + e0[col], *cp);
                }
            }
        }
}

// ---------------------------------------------------------------------------
__global__ void init_kernel(float* __restrict__ out_zero, size_t nzero,
                            float* __restrict__ hA, float* __restrict__ rA,
                            float* __restrict__ RA, float* __restrict__ NA,
                            float* __restrict__ stA,
                            const float* __restrict__ prev_steps, int B)
{
    size_t i = (size_t)blockIdx.x * 256 + threadIdx.x;
    if (i < nzero) out_zero[i] = 0.f;
    if (i < (size_t)B) {
        hA[i] = 0.f; rA[i] = 1.f; RA[i] = 1.f; NA[i] = 0.f;
        stA[i] = prev_steps[i] + 1.f;
    }
}

__global__ void split_f32(const float* __restrict__ src,
                          ushort* __restrict__ hi, ushort* __restrict__ lo, size_t n4)
{
    size_t i = (size_t)blockIdx.x * 256 + threadIdx.x;
    if (i < n4) {
        float4 v = reinterpret_cast<const float4*>(src)[i];
        ushort4 h, l;
        h.x = f2bf(v.x); l.x = f2bf(v.x - bf2f(h.x));
        h.y = f2bf(v.y); l.y = f2bf(v.y - bf2f(h.y));
        h.z = f2bf(v.z); l.z = f2bf(v.z - bf2f(h.z));
        h.w = f2bf(v.w); l.w = f2bf(v.w - bf2f(h.w));
        reinterpret_cast<ushort4*>(hi)[i] = h;
        reinterpret_cast<ushort4*>(lo)[i] = l;
    }
}

// W_ih[H, D+1] -> split [H,D] + wcol[H]
__global__ void wih_split(const float* __restrict__ Wih,
                          ushort* __restrict__ hi, ushort* __restrict__ lo,
                          float* __restrict__ wcol, int H, int D)
{
    size_t i = (size_t)blockIdx.x * 256 + threadIdx.x;
    if (i < (size_t)H * D) {
        int h = (int)(i / D), d = (int)(i % D);
        float v = Wih[(size_t)h * (D + 1) + d];
        ushort hb = f2bf(v);
        hi[i] = hb; lo[i] = f2bf(v - bf2f(hb));
    }
    if (i < (size_t)H) wcol[i] = Wih[i * (size_t)(D + 1) + D];
}

// per-row halt state machine + s_acc += p * s   (s reconstructed as hi+lo)
__global__ __launch_bounds__(256)
void halt_update(const ushort* __restrict__ shi, const ushort* __restrict__ slo,
                 const float* __restrict__ Whalt, const float* __restrict__ bhalt,
                 float* __restrict__ hA, float* __restrict__ rA, float* __restrict__ RA,
                 float* __restrict__ NA, float* __restrict__ stA, float* __restrict__ pA,
                 float* __restrict__ s_acc, float n1, int H, int isFinal)
{
    const int b = blockIdx.x;
    const int tid = threadIdx.x;
    const size_t base = (size_t)b * H;
    const int i = tid * 4;                     // H == 1024 == 256*4
    ushort4 h4 = *reinterpret_cast<const ushort4*>(shi + base + i);
    ushort4 l4 = *reinterpret_cast<const ushort4*>(slo + base + i);
    float s0 = bf2f(h4.x) + bf2f(l4.x);
    float s1 = bf2f(h4.y) + bf2f(l4.y);
    float s2 = bf2f(h4.z) + bf2f(l4.z);
    float s3 = bf2f(h4.w) + bf2f(l4.w);

    __shared__ float partial[4];
    __shared__ float psh;
    float4 w4 = *reinterpret_cast<const float4*>(Whalt + i);
    float lsum = s0 * w4.x + s1 * w4.y + s2 * w4.z + s3 * w4.w;
#pragma unroll
    for (int off = 32; off > 0; off >>= 1) lsum += __shfl_down(lsum, off, 64);
    if ((tid & 63) == 0) partial[tid >> 6] = lsum;
    __syncthreads();
    if (tid == 0) {
        float pv;
        if (isFinal) {
            pv = rA[b];
        } else {
            float dot = partial[0] + partial[1] + partial[2] + partial[3] + bhalt[0];
            float h_n = 1.f / (1.f + expf(-dot));
            float hh = hA[b] + h_n;
            bool isN = hh >= 0.99f;            // 1 - EPS
            pv = isN ? rA[b] : h_n;
            float r_new = isN ? 0.f : 1.f - hh;
            if (!isN) { RA[b] = r_new; NA[b] = n1; stA[b] += 1.f; }
            hA[b] = hh; rA[b] = r_new; pA[b] = pv;
        }
        psh = pv;
    }
    __syncthreads();
    const float pv = psh;
    if (pv != 0.f) {
        float4* sac = reinterpret_cast<float4*>(s_acc + base + i);
        float4 o = *sac;
        o.x = fmaf(pv, s0, o.x); o.y = fmaf(pv, s1, o.y);
        o.z = fmaf(pv, s2, o.z); o.w = fmaf(pv, s3, o.w);
        *sac = o;
    }
}

__global__ void finalize_kernel(const float* __restrict__ pp, const float* __restrict__ RA,
                                const float* __restrict__ NA, const float* __restrict__ stA,
                                float* __restrict__ pon, float* __restrict__ stp, int B)
{
    int i = blockIdx.x * 256 + threadIdx.x;
    if (i < B) { pon[i] = pp[i] + RA[i] + NA[i]; stp[i] = stA[i]; }
}

// ---------------------------------------------------------------------------
extern "C" void kernel_launch(void* const* d_in, const int* in_sizes, int n_in,
                              void* d_out, int out_size, void* d_ws, size_t ws_size,
                              hipStream_t stream)
{
    const float* x     = (const float*)d_in[0];
    const float* ph    = (const float*)d_in[1];
    const float* pp    = (const float*)d_in[2];
    const float* ps    = (const float*)d_in[3];
    const float* Wih   = (const float*)d_in[4];
    const float* bih   = (const float*)d_in[5];
    const float* Whh   = (const float*)d_in[6];
    const float* bhh   = (const float*)d_in[7];
    const float* Whalt = (const float*)d_in[8];
    const float* bhalt = (const float*)d_in[9];
    const float* Wans  = (const float*)d_in[10];
    const float* bans  = (const float*)d_in[11];

    const int B = in_sizes[2];
    const int H = in_sizes[5];
    const int O = in_sizes[11];
    const int D = in_sizes[0] / B;

    float* out_y   = (float*)d_out;
    float* out_sac = out_y + (size_t)B * O;
    float* out_pon = out_sac + (size_t)B * H;
    float* out_stp = out_pon + B;

    // workspace layout (16B-aligned chunks)
    char* w = (char*)d_ws;
    float* xproj = (float*)w;  w += (size_t)B * H * 4;
    ushort* shi[2], *slo[2];
    shi[0] = (ushort*)w; w += (size_t)B * H * 2;
    slo[0] = (ushort*)w; w += (size_t)B * H * 2;
    shi[1] = (ushort*)w; w += (size_t)B * H * 2;
    slo[1] = (ushort*)w; w += (size_t)B * H * 2;
    ushort* whhhi = (ushort*)w; w += (size_t)H * H * 2;
    ushort* whhlo = (ushort*)w; w += (size_t)H * H * 2;
    ushort* wanshi = (ushort*)w; w += (size_t)O * H * 2;
    ushort* wanslo = (ushort*)w; w += (size_t)O * H * 2;
    ushort* wihhi = (ushort*)w; w += (size_t)H * D * 2;
    ushort* wihlo = (ushort*)w; w += (size_t)H * D * 2;
    float* wcol = (float*)w; w += (size_t)H * 4;
    float* hA  = (float*)w; w += (size_t)B * 4;
    float* rA  = (float*)w; w += (size_t)B * 4;
    float* RA  = (float*)w; w += (size_t)B * 4;
    float* NA  = (float*)w; w += (size_t)B * 4;
    float* stA = (float*)w; w += (size_t)B * 4;
    float* pA  = (float*)w; w += (size_t)B * 4;

    // x split buffers alias s[1] ping-pong (dead before s[1] first written)
    ushort* xhi = shi[1];
    ushort* xlo = slo[1];

    const size_t nzero = (size_t)B * (O + H);
    init_kernel<<<(unsigned)((nzero + 255) / 256), 256, 0, stream>>>(
        out_y, nzero, hA, rA, RA, NA, stA, ps, B);

    split_f32<<<(unsigned)(((size_t)B * D / 4 + 255) / 256), 256, 0, stream>>>(x, xhi, xlo, (size_t)B * D / 4);
    split_f32<<<(unsigned)(((size_t)B * H / 4 + 255) / 256), 256, 0, stream>>>(ph, shi[0], slo[0], (size_t)B * H / 4);
    split_f32<<<(unsigned)(((size_t)H * H / 4 + 255) / 256), 256, 0, stream>>>(Whh, whhhi, whhlo, (size_t)H * H / 4);
    split_f32<<<(unsigned)(((size_t)O * H / 4 + 255) / 256), 256, 0, stream>>>(Wans, wanshi, wanslo, (size_t)O * H / 4);
    wih_split<<<(unsigned)(((size_t)H * D + 255) / 256), 256, 0, stream>>>(Wih, wihhi, wihlo, wcol, H, D);

    // xproj = x @ W_ih[:, :D]^T + b_ih + b_hh
    {
        dim3 g(B / 64, H / 128);
        mfma_gemm<64, 128, 0><<<g, 256, 0, stream>>>(
            xhi, xlo, D, wihhi, wihlo, D, D / 64,
            xproj, H, bih, bhh, 0.f, nullptr, nullptr);
    }

    int cur = 0;
    for (int t = 0; t < MAX_ITER; t++) {
        const int nxt = cur ^ 1;
        const float flag = (t == 0) ? 1.f : 0.f;
        // s_new = tanh(xproj + flag*wcol + s @ Whh^T)  -> split into shi/slo[nxt]
        {
            dim3 g(B / 64, H / 128);
            mfma_gemm<64, 128, 1><<<g, 256, 0, stream>>>(
                shi[cur], slo[cur], H, whhhi, whhlo, H, H / 64,
                nullptr, H, xproj, wcol, flag, shi[nxt], slo[nxt]);
        }
        const int isFinal = (t == MAX_ITER - 1);
        halt_update<<<B, 256, 0, stream>>>(
            shi[nxt], slo[nxt], Whalt, bhalt, hA, rA, RA, NA, stA, pA,
            out_sac, (float)(t + 2), H, isFinal);
        // y += p * (s_new @ Wans^T + b_ans)
        {
            dim3 g(B / 64, O / 64);
            mfma_gemm<64, 64, 2><<<g, 256, 0, stream>>>(
                shi[nxt], slo[nxt], H, wanshi, wanslo, H, H / 64,
                out_y, O, bans, isFinal ? rA : pA, 0.f, nullptr, nullptr);
        }
        cur = nxt;
    }

    finalize_kernel<<<(B + 255) / 256, 256, 0, stream>>>(
        pp, RA, NA, stA, out_pon, out_stp, B);
}

// Round 8
// 860.235 us; speedup vs baseline: 2.7298x; 1.1536x over previous
//
#include <hip/hip_runtime.h>
#include <cmath>
#include <cstddef>

// ACT cell, B=4096 D=512 H=1024 O=512 MAX_ITER=10 EPS=0.01
//
// GEMMs: bf16 MFMA split-3 fp32 emulation (hi*hi + hi*lo + lo*hi), K'=3K.
// Round 8:
//  - counted-vmcnt pipeline (T4): raw s_barrier + s_waitcnt vmcnt(NL),
//    never vmcnt(0) in the main loop; sched_barrier(0) fences (rule #18).
//  - T5 setprio(1) around the MFMA cluster.
//  - merged dispatch: MODE2(t-1) and MODE1(t) are independent -> one
//    1024-block kernel (role split by blockIdx), 9x per run.

#define MAX_ITER 10

typedef short bf16x8 __attribute__((ext_vector_type(8)));
typedef float f32x4  __attribute__((ext_vector_type(4)));

__device__ __forceinline__ ushort f2bf(float f) {
    unsigned u = __float_as_uint(f);
    u += 0x7fff + ((u >> 16) & 1);          // RNE
    return (ushort)(u >> 16);
}
__device__ __forceinline__ float bf2f(ushort b) {
    return __uint_as_float(((unsigned)b) << 16);
}
__device__ __forceinline__ void gld16(const void* g, void* l) {
    __builtin_amdgcn_global_load_lds(
        (const __attribute__((address_space(1))) void*)g,
        (__attribute__((address_space(3))) void*)l, 16, 0, 0);
}

// ---------------------------------------------------------------------------
// GEMM body. C[M,N] = epi(A[M,K']*B[N,K']^T) over 3 split segments.
// MODE 0: Cout = acc + e0[col] + e1[col]
// MODE 1: s = tanh(acc + e0[row*ldn+col] + flag*e1[col]); write split(s)
// MODE 2: Cout[row,col] += e1[row] * (acc + e0[col])
// 256 threads, 4 waves 2x2; double-buffered LDS; counted-vmcnt pipeline.
// ---------------------------------------------------------------------------
template<int BM, int BN, int MODE>
__device__ __forceinline__ void gemm_body(
    int bx, int by,
    const ushort* __restrict__ ahi, const ushort* __restrict__ alo, int lda,
    const ushort* __restrict__ bhi, const ushort* __restrict__ blo, int ldb,
    int tps, float* __restrict__ Cout, int ldn,
    const float* __restrict__ e0, const float* __restrict__ e1, float flag,
    ushort* __restrict__ shiO, ushort* __restrict__ sloO,
    ushort* smem)
{
    constexpr int FRM = BM / 32;
    constexpr int FRN = BN / 32;
    constexpr int NL  = BM / 32 + BN / 32;   // global_load_lds per thread/stage
    ushort* As = smem;                        // [2][BM*64]
    ushort* Bs = smem + 2 * BM * 64;          // [2][BN*64]

    const int tid  = threadIdx.x;
    const int lane = tid & 63;
    const int wave = tid >> 6;
    const int lq   = lane & 15;
    const int kh   = lane >> 4;
    const int wr0  = (wave >> 1) * (BM / 2);
    const int wc0  = (wave & 1) * (BN / 2);
    const int m0   = bx * BM;
    const int n0   = by * BN;

    f32x4 acc[FRM][FRN];
#pragma unroll
    for (int r = 0; r < FRM; ++r)
#pragma unroll
        for (int c = 0; c < FRN; ++c) acc[r][c] = (f32x4)0.f;

    const int steps = 3 * tps;

    auto stage = [&](int buf, int t) {
        const int seg = (t >= 2 * tps) ? 2 : ((t >= tps) ? 1 : 0);
        const int k0  = (t - seg * tps) * 64;
        const ushort* aS = (seg == 2) ? alo : ahi;
        const ushort* bS = (seg == 1) ? blo : bhi;
#pragma unroll
        for (int j = 0; j < BM / 32; ++j) {
            int c   = j * 256 + tid;
            int row = c >> 3;                       // 8 x 16B chunks per 128B row
            int kb  = ((c & 7) << 4) ^ ((row & 7) << 4);
            gld16(aS + (size_t)(m0 + row) * lda + k0 + (kb >> 1),
                  As + buf * (BM * 64) + (size_t)(j * 256 + (tid & ~63)) * 8);
        }
#pragma unroll
        for (int j = 0; j < BN / 32; ++j) {
            int c   = j * 256 + tid;
            int row = c >> 3;
            int kb  = ((c & 7) << 4) ^ ((row & 7) << 4);
            gld16(bS + (size_t)(n0 + row) * ldb + k0 + (kb >> 1),
                  Bs + buf * (BN * 64) + (size_t)(j * 256 + (tid & ~63)) * 8);
        }
    };

    stage(0, 0);
    stage(1, 1);                         // 2 tiles in flight

    int cur = 0;
    for (int t = 0; t < steps; ++t) {
        // wait for stage(t) only: next tile's NL loads may stay outstanding.
        if (t + 1 < steps) __builtin_amdgcn_s_waitcnt(0xF70 | NL);
        else               __builtin_amdgcn_s_waitcnt(0xF70);
        __builtin_amdgcn_sched_barrier(0);
        __builtin_amdgcn_s_barrier();        // all waves' stage(t) landed
        __builtin_amdgcn_sched_barrier(0);

        const ushort* Ab = As + cur * (BM * 64);
        const ushort* Bb = Bs + cur * (BN * 64);
#pragma unroll
        for (int kt = 0; kt < 2; ++kt) {
            bf16x8 af[FRM], bfr[FRN];
#pragma unroll
            for (int r = 0; r < FRM; ++r) {
                int row = wr0 + r * 16 + lq;
                int kb  = (kt * 64 + kh * 16) ^ ((row & 7) << 4);
                af[r] = *reinterpret_cast<const bf16x8*>(&Ab[row * 64 + (kb >> 1)]);
            }
#pragma unroll
            for (int c = 0; c < FRN; ++c) {
                int row = wc0 + c * 16 + lq;
                int kb  = (kt * 64 + kh * 16) ^ ((row & 7) << 4);
                bfr[c] = *reinterpret_cast<const bf16x8*>(&Bb[row * 64 + (kb >> 1)]);
            }
            __builtin_amdgcn_s_setprio(1);
#pragma unroll
            for (int r = 0; r < FRM; ++r)
#pragma unroll
                for (int c = 0; c < FRN; ++c)
                    acc[r][c] = __builtin_amdgcn_mfma_f32_16x16x32_bf16(
                        af[r], bfr[c], acc[r][c], 0, 0, 0);
            __builtin_amdgcn_s_setprio(0);
        }
        __builtin_amdgcn_sched_barrier(0);
        __builtin_amdgcn_s_barrier();        // all waves done reading buf[cur]
        __builtin_amdgcn_sched_barrier(0);
        if (t + 2 < steps) stage(cur, t + 2);   // overwrite now safe
        cur ^= 1;
    }

    // epilogue — C/D layout: col = lane&15, row = (lane>>4)*4 + q  [m89]
#pragma unroll
    for (int r = 0; r < FRM; ++r)
#pragma unroll
        for (int c = 0; c < FRN; ++c) {
            const size_t col = n0 + wc0 + c * 16 + lq;
#pragma unroll
            for (int q = 0; q < 4; ++q) {
                const size_t row = m0 + wr0 + r * 16 + kh * 4 + q;
                float v = acc[r][c][q];
                if constexpr (MODE == 0) {
                    v += e0[col] + e1[col];
                    Cout[row * ldn + col] = v;
                } else if constexpr (MODE == 1) {
                    v += e0[row * ldn + col];
                    if (flag != 0.f) v += flag * e1[col];
                    float s = tanhf(v);
                    ushort hb = f2bf(s);
                    ushort lb = f2bf(s - bf2f(hb));
                    shiO[row * ldn + col] = hb;
                    sloO[row * ldn + col] = lb;
                } else {
                    const float pv = e1[row];
                    float* cp = &Cout[row * ldn + col];
                    *cp = fmaf(pv, v + e0[col], *cp);
                }
            }
        }
}

template<int BM, int BN, int MODE>
__global__ __launch_bounds__(256)
void mfma_gemm(const ushort* __restrict__ ahi, const ushort* __restrict__ alo, int lda,
               const ushort* __restrict__ bhi, const ushort* __restrict__ blo, int ldb,
               int tps, float* __restrict__ Cout, int ldn,
               const float* __restrict__ e0, const float* __restrict__ e1,
               float flag, ushort* __restrict__ shiO, ushort* __restrict__ sloO)
{
    __shared__ __align__(16) ushort smem[2 * (BM + BN) * 64];
    gemm_body<BM, BN, MODE>(blockIdx.x, blockIdx.y, ahi, alo, lda, bhi, blo, ldb,
                            tps, Cout, ldn, e0, e1, flag, shiO, sloO, smem);
}

// MODE1(t) [blocks 0..m1-1] in parallel with MODE2(t-1) [blocks m1..].
// Both read the same s (hi/lo); MODE1 writes s_next, MODE2 accumulates y.
__global__ __launch_bounds__(256)
void merged_gemm(int m1_blocks, int m1_gx, int m2_gx,
                 const ushort* __restrict__ s_hi, const ushort* __restrict__ s_lo,
                 const ushort* __restrict__ whhhi, const ushort* __restrict__ whhlo,
                 int H, int tps,
                 float* __restrict__ xproj, const float* __restrict__ wcol,
                 ushort* __restrict__ o_hi, ushort* __restrict__ o_lo,
                 const ushort* __restrict__ wanshi, const ushort* __restrict__ wanslo,
                 float* __restrict__ out_y, int O,
                 const float* __restrict__ bans, const float* __restrict__ pA)
{
    extern __shared__ ushort smem[];
    const int b = blockIdx.x;
    if (b < m1_blocks) {
        gemm_body<64, 128, 1>(b % m1_gx, b / m1_gx, s_hi, s_lo, H,
                              whhhi, whhlo, H, tps, nullptr, H,
                              xproj, wcol, 0.f, o_hi, o_lo, smem);
    } else {
        const int b2 = b - m1_blocks;
        gemm_body<64, 64, 2>(b2 % m2_gx, b2 / m2_gx, s_hi, s_lo, H,
                             wanshi, wanslo, H, tps, out_y, O,
                             bans, pA, 0.f, nullptr, nullptr, smem);
    }
}

// ---------------------------------------------------------------------------
__global__ void init_kernel(float* __restrict__ out_zero, size_t nzero,
                            float* __restrict__ hA, float* __restrict__ rA,
                            float* __restrict__ RA, float* __restrict__ NA,
                            float* __restrict__ stA,
                            const float* __restrict__ prev_steps, int B)
{
    size_t i = (size_t)blockIdx.x * 256 + threadIdx.x;
    if (i < nzero) out_zero[i] = 0.f;
    if (i < (size_t)B) {
        hA[i] = 0.f; rA[i] = 1.f; RA[i] = 1.f; NA[i] = 0.f;
        stA[i] = prev_steps[i] + 1.f;
    }
}

__global__ void split_f32(const float* __restrict__ src,
                          ushort* __restrict__ hi, ushort* __restrict__ lo, size_t n4)
{
    size_t i = (size_t)blockIdx.x * 256 + threadIdx.x;
    if (i < n4) {
        float4 v = reinterpret_cast<const float4*>(src)[i];
        ushort4 h, l;
        h.x = f2bf(v.x); l.x = f2bf(v.x - bf2f(h.x));
        h.y = f2bf(v.y); l.y = f2bf(v.y - bf2f(h.y));
        h.z = f2bf(v.z); l.z = f2bf(v.z - bf2f(h.z));
        h.w = f2bf(v.w); l.w = f2bf(v.w - bf2f(h.w));
        reinterpret_cast<ushort4*>(hi)[i] = h;
        reinterpret_cast<ushort4*>(lo)[i] = l;
    }
}

// W_ih[H, D+1] -> split [H,D] + wcol[H]
__global__ void wih_split(const float* __restrict__ Wih,
                          ushort* __restrict__ hi, ushort* __restrict__ lo,
                          float* __restrict__ wcol, int H, int D)
{
    size_t i = (size_t)blockIdx.x * 256 + threadIdx.x;
    if (i < (size_t)H * D) {
        int h = (int)(i / D), d = (int)(i % D);
        float v = Wih[(size_t)h * (D + 1) + d];
        ushort hb = f2bf(v);
        hi[i] = hb; lo[i] = f2bf(v - bf2f(hb));
    }
    if (i < (size_t)H) wcol[i] = Wih[i * (size_t)(D + 1) + D];
}

// per-row halt state machine + s_acc += p * s   (s reconstructed as hi+lo)
__global__ __launch_bounds__(256)
void halt_update(const ushort* __restrict__ shi, const ushort* __restrict__ slo,
                 const float* __restrict__ Whalt, const float* __restrict__ bhalt,
                 float* __restrict__ hA, float* __restrict__ rA, float* __restrict__ RA,
                 float* __restrict__ NA, float* __restrict__ stA, float* __restrict__ pA,
                 float* __restrict__ s_acc, float n1, int H, int isFinal)
{
    const int b = blockIdx.x;
    const int tid = threadIdx.x;
    const size_t base = (size_t)b * H;
    const int i = tid * 4;                     // H == 1024 == 256*4
    ushort4 h4 = *reinterpret_cast<const ushort4*>(shi + base + i);
    ushort4 l4 = *reinterpret_cast<const ushort4*>(slo + base + i);
    float s0 = bf2f(h4.x) + bf2f(l4.x);
    float s1 = bf2f(h4.y) + bf2f(l4.y);
    float s2 = bf2f(h4.z) + bf2f(l4.z);
    float s3 = bf2f(h4.w) + bf2f(l4.w);

    __shared__ float partial[4];
    __shared__ float psh;
    float4 w4 = *reinterpret_cast<const float4*>(Whalt + i);
    float lsum = s0 * w4.x + s1 * w4.y + s2 * w4.z + s3 * w4.w;
#pragma unroll
    for (int off = 32; off > 0; off >>= 1) lsum += __shfl_down(lsum, off, 64);
    if ((tid & 63) == 0) partial[tid >> 6] = lsum;
    __syncthreads();
    if (tid == 0) {
        float pv;
        if (isFinal) {
            pv = rA[b];
        } else {
            float dot = partial[0] + partial[1] + partial[2] + partial[3] + bhalt[0];
            float h_n = 1.f / (1.f + expf(-dot));
            float hh = hA[b] + h_n;
            bool isN = hh >= 0.99f;            // 1 - EPS
            pv = isN ? rA[b] : h_n;
            float r_new = isN ? 0.f : 1.f - hh;
            if (!isN) { RA[b] = r_new; NA[b] = n1; stA[b] += 1.f; }
            hA[b] = hh; rA[b] = r_new; pA[b] = pv;
        }
        psh = pv;
    }
    __syncthreads();
    const float pv = psh;
    if (pv != 0.f) {
        float4* sac = reinterpret_cast<float4*>(s_acc + base + i);
        float4 o = *sac;
        o.x = fmaf(pv, s0, o.x); o.y = fmaf(pv, s1, o.y);
        o.z = fmaf(pv, s2, o.z); o.w = fmaf(pv, s3, o.w);
        *sac = o;
    }
}

__global__ void finalize_kernel(const float* __restrict__ pp, const float* __restrict__ RA,
                                const float* __restrict__ NA, const float* __restrict__ stA,
                                float* __restrict__ pon, float* __restrict__ stp, int B)
{
    int i = blockIdx.x * 256 + threadIdx.x;
    if (i < B) { pon[i] = pp[i] + RA[i] + NA[i]; stp[i] = stA[i]; }
}

// ---------------------------------------------------------------------------
extern "C" void kernel_launch(void* const* d_in, const int* in_sizes, int n_in,
                              void* d_out, int out_size, void* d_ws, size_t ws_size,
                              hipStream_t stream)
{
    const float* x     = (const float*)d_in[0];
    const float* ph    = (const float*)d_in[1];
    const float* pp    = (const float*)d_in[2];
    const float* ps    = (const float*)d_in[3];
    const float* Wih   = (const float*)d_in[4];
    const float* bih   = (const float*)d_in[5];
    const float* Whh   = (const float*)d_in[6];
    const float* bhh   = (const float*)d_in[7];
    const float* Whalt = (const float*)d_in[8];
    const float* bhalt = (const float*)d_in[9];
    const float* Wans  = (const float*)d_in[10];
    const float* bans  = (const float*)d_in[11];

    const int B = in_sizes[2];
    const int H = in_sizes[5];
    const int O = in_sizes[11];
    const int D = in_sizes[0] / B;

    float* out_y   = (float*)d_out;
    float* out_sac = out_y + (size_t)B * O;
    float* out_pon = out_sac + (size_t)B * H;
    float* out_stp = out_pon + B;

    // workspace layout (16B-aligned chunks)
    char* w = (char*)d_ws;
    float* xproj = (float*)w;  w += (size_t)B * H * 4;
    ushort* shi[2], *slo[2];
    shi[0] = (ushort*)w; w += (size_t)B * H * 2;
    slo[0] = (ushort*)w; w += (size_t)B * H * 2;
    shi[1] = (ushort*)w; w += (size_t)B * H * 2;
    slo[1] = (ushort*)w; w += (size_t)B * H * 2;
    ushort* whhhi = (ushort*)w; w += (size_t)H * H * 2;
    ushort* whhlo = (ushort*)w; w += (size_t)H * H * 2;
    ushort* wanshi = (ushort*)w; w += (size_t)O * H * 2;
    ushort* wanslo = (ushort*)w; w += (size_t)O * H * 2;
    ushort* wihhi = (ushort*)w; w += (size_t)H * D * 2;
    ushort* wihlo = (ushort*)w; w += (size_t)H * D * 2;
    float* wcol = (float*)w; w += (size_t)H * 4;
    float* hA  = (float*)w; w += (size_t)B * 4;
    float* rA  = (float*)w; w += (size_t)B * 4;
    float* RA  = (float*)w; w += (size_t)B * 4;
    float* NA  = (float*)w; w += (size_t)B * 4;
    float* stA = (float*)w; w += (size_t)B * 4;
    float* pA  = (float*)w; w += (size_t)B * 4;

    // x split buffers alias s[1] ping-pong (dead before s[1] first written)
    ushort* xhi = shi[1];
    ushort* xlo = slo[1];

    const size_t nzero = (size_t)B * (O + H);
    init_kernel<<<(unsigned)((nzero + 255) / 256), 256, 0, stream>>>(
        out_y, nzero, hA, rA, RA, NA, stA, ps, B);

    split_f32<<<(unsigned)(((size_t)B * D / 4 + 255) / 256), 256, 0, stream>>>(x, xhi, xlo, (size_t)B * D / 4);
    split_f32<<<(unsigned)(((size_t)B * H / 4 + 255) / 256), 256, 0, stream>>>(ph, shi[0], slo[0], (size_t)B * H / 4);
    split_f32<<<(unsigned)(((size_t)H * H / 4 + 255) / 256), 256, 0, stream>>>(Whh, whhhi, whhlo, (size_t)H * H / 4);
    split_f32<<<(unsigned)(((size_t)O * H / 4 + 255) / 256), 256, 0, stream>>>(Wans, wanshi, wanslo, (size_t)O * H / 4);
    wih_split<<<(unsigned)(((size_t)H * D + 255) / 256), 256, 0, stream>>>(Wih, wihhi, wihlo, wcol, H, D);

    // xproj = x @ W_ih[:, :D]^T + b_ih + b_hh
    {
        dim3 g(B / 64, H / 128);
        mfma_gemm<64, 128, 0><<<g, 256, 0, stream>>>(
            xhi, xlo, D, wihhi, wihlo, D, D / 64,
            xproj, H, bih, bhh, 0.f, nullptr, nullptr);
    }

    const int m1_gx = B / 64, m1_gy = H / 128;   // 64 x 8
    const int m2_gx = B / 64, m2_gy = O / 64;    // 64 x 8
    const int m1_blocks = m1_gx * m1_gy;
    const int m2_blocks = m2_gx * m2_gy;
    const size_t lds_merged = 2u * (64 + 128) * 64 * sizeof(ushort);  // 48 KB

    // step 0: MODE1 alone (flag=1)
    {
        dim3 g(B / 64, H / 128);
        mfma_gemm<64, 128, 1><<<g, 256, 0, stream>>>(
            shi[0], slo[0], H, whhhi, whhlo, H, H / 64,
            nullptr, H, xproj, wcol, 1.f, shi[1], slo[1]);
    }

    int cur = 1;   // s after step 0 lives in buffer 1
    for (int t = 1; t < MAX_ITER; t++) {
        // halt for step t-1 (uses s[cur]); n = (t-1)+2
        halt_update<<<B, 256, 0, stream>>>(
            shi[cur], slo[cur], Whalt, bhalt, hA, rA, RA, NA, stA, pA,
            out_sac, (float)(t + 1), H, 0);
        // MODE1(t): s[cur] -> s[cur^1]   ||   MODE2(t-1): y += pA * (s[cur]@Wans^T+b)
        merged_gemm<<<m1_blocks + m2_blocks, 256, lds_merged, stream>>>(
            m1_blocks, m1_gx, m2_gx,
            shi[cur], slo[cur], whhhi, whhlo, H, H / 64,
            xproj, wcol, shi[cur ^ 1], slo[cur ^ 1],
            wanshi, wanslo, out_y, O, bans, pA);
        cur ^= 1;
    }

    // final: halt for step 9 (isFinal -> p = r, s_acc += r*s), then MODE2(9)
    halt_update<<<B, 256, 0, stream>>>(
        shi[cur], slo[cur], Whalt, bhalt, hA, rA, RA, NA, stA, pA,
        out_sac, 0.f, H, 1);
    {
        dim3 g(B / 64, O / 64);
        mfma_gemm<64, 64, 2><<<g, 256, 0, stream>>>(
            shi[cur], slo[cur], H, wanshi, wanslo, H, H / 64,
            out_y, O, bans, rA, 0.f, nullptr, nullptr);
    }

    finalize_kernel<<<(B + 255) / 256, 256, 0, stream>>>(
        pp, RA, NA, stA, out_pon, out_stp, B);
}

// Round 9
// 713.606 us; speedup vs baseline: 3.2907x; 1.2055x over previous
//
#include <hip/hip_runtime.h>
#include <cmath>
#include <cstddef>

// ACT cell, B=4096 D=512 H=1024 O=512 MAX_ITER=10 EPS=0.01
//
// GEMMs: bf16 MFMA split-3 fp32 emulation (hi*hi + hi*lo + lo*hi), K'=3K.
// Round 9:
//  - ALGEBRAIC: y = sum_t p_t (s_t@Wans^T + b) = s_acc @ Wans^T + P*b_ans.
//    Per-step y-GEMM eliminated; one GEMM at the end (A = split(s_acc)).
//  - 3-deep LDS pipeline: vmcnt(2*NL) waits, 2 compute phases in flight.
//  - bijective XCD swizzle on the 1-D grid (512 % 8 == 0).
//  - xproj stored as bf16 hi/lo split (half the epilogue read bytes).

#define MAX_ITER 10

typedef short bf16x8 __attribute__((ext_vector_type(8)));
typedef float f32x4  __attribute__((ext_vector_type(4)));

__device__ __forceinline__ ushort f2bf(float f) {
    unsigned u = __float_as_uint(f);
    u += 0x7fff + ((u >> 16) & 1);          // RNE
    return (ushort)(u >> 16);
}
__device__ __forceinline__ float bf2f(ushort b) {
    return __uint_as_float(((unsigned)b) << 16);
}
__device__ __forceinline__ void gld16(const void* g, void* l) {
    __builtin_amdgcn_global_load_lds(
        (const __attribute__((address_space(1))) void*)g,
        (__attribute__((address_space(3))) void*)l, 16, 0, 0);
}

// ---------------------------------------------------------------------------
// MODE 0: write split(acc + e0[col] + e1[col]) -> shiO/sloO      (xproj)
// MODE 1: v = acc + bf2f(uA[rc]) + bf2f(uB[rc]) (+flag*e1[col]);
//         s = tanh(v); write split(s) -> shiO/sloO               (recurrent)
// MODE 3: Cout[rc] = acc + e1[row]*e0[col]                       (final y)
// 256 threads, 4 waves 2x2; 3-buffer LDS; counted-vmcnt pipeline.
// ---------------------------------------------------------------------------
template<int BM, int BN, int MODE>
__device__ __forceinline__ void gemm_body(
    int bx, int by,
    const ushort* __restrict__ ahi, const ushort* __restrict__ alo, int lda,
    const ushort* __restrict__ bhi, const ushort* __restrict__ blo, int ldb,
    int tps, float* __restrict__ Cout, int ldn,
    const float* __restrict__ e0, const float* __restrict__ e1, float flag,
    const ushort* __restrict__ uA, const ushort* __restrict__ uB,
    ushort* __restrict__ shiO, ushort* __restrict__ sloO,
    ushort* smem)
{
    constexpr int FRM = BM / 32;
    constexpr int FRN = BN / 32;
    constexpr int NL  = (BM + BN) / 32;      // global_load_lds per thread/stage
    ushort* As = smem;                        // [3][BM*64]
    ushort* Bs = smem + 3 * BM * 64;          // [3][BN*64]

    const int tid  = threadIdx.x;
    const int lane = tid & 63;
    const int wave = tid >> 6;
    const int lq   = lane & 15;
    const int kh   = lane >> 4;
    const int wr0  = (wave >> 1) * (BM / 2);
    const int wc0  = (wave & 1) * (BN / 2);
    const int m0   = bx * BM;
    const int n0   = by * BN;

    f32x4 acc[FRM][FRN];
#pragma unroll
    for (int r = 0; r < FRM; ++r)
#pragma unroll
        for (int c = 0; c < FRN; ++c) acc[r][c] = (f32x4)0.f;

    const int steps = 3 * tps;

    auto stage = [&](int buf, int t) {
        const int seg = (t >= 2 * tps) ? 2 : ((t >= tps) ? 1 : 0);
        const int k0  = (t - seg * tps) * 64;
        const ushort* aS = (seg == 2) ? alo : ahi;
        const ushort* bS = (seg == 1) ? blo : bhi;
#pragma unroll
        for (int j = 0; j < BM / 32; ++j) {
            int c   = j * 256 + tid;
            int row = c >> 3;                       // 8 x 16B chunks per 128B row
            int kb  = ((c & 7) << 4) ^ ((row & 7) << 4);
            gld16(aS + (size_t)(m0 + row) * lda + k0 + (kb >> 1),
                  As + buf * (BM * 64) + (size_t)(j * 256 + (tid & ~63)) * 8);
        }
#pragma unroll
        for (int j = 0; j < BN / 32; ++j) {
            int c   = j * 256 + tid;
            int row = c >> 3;
            int kb  = ((c & 7) << 4) ^ ((row & 7) << 4);
            gld16(bS + (size_t)(n0 + row) * ldb + k0 + (kb >> 1),
                  Bs + buf * (BN * 64) + (size_t)(j * 256 + (tid & ~63)) * 8);
        }
    };

    stage(0, 0);
    stage(1, 1);
    stage(2, 2);                         // 3 tiles in flight

    int cur = 0;
    for (int t = 0; t < steps; ++t) {
        const int rem = steps - 1 - t;
        if (rem >= 2)      __builtin_amdgcn_s_waitcnt(0xF70 | (2 * NL));
        else if (rem == 1) __builtin_amdgcn_s_waitcnt(0xF70 | NL);
        else               __builtin_amdgcn_s_waitcnt(0xF70);
        __builtin_amdgcn_sched_barrier(0);
        __builtin_amdgcn_s_barrier();        // all waves' stage(t) landed
        __builtin_amdgcn_sched_barrier(0);

        const ushort* Ab = As + cur * (BM * 64);
        const ushort* Bb = Bs + cur * (BN * 64);
#pragma unroll
        for (int kt = 0; kt < 2; ++kt) {
            bf16x8 af[FRM], bfr[FRN];
#pragma unroll
            for (int r = 0; r < FRM; ++r) {
                int row = wr0 + r * 16 + lq;
                int kb  = (kt * 64 + kh * 16) ^ ((row & 7) << 4);
                af[r] = *reinterpret_cast<const bf16x8*>(&Ab[row * 64 + (kb >> 1)]);
            }
#pragma unroll
            for (int c = 0; c < FRN; ++c) {
                int row = wc0 + c * 16 + lq;
                int kb  = (kt * 64 + kh * 16) ^ ((row & 7) << 4);
                bfr[c] = *reinterpret_cast<const bf16x8*>(&Bb[row * 64 + (kb >> 1)]);
            }
            __builtin_amdgcn_s_setprio(1);
#pragma unroll
            for (int r = 0; r < FRM; ++r)
#pragma unroll
                for (int c = 0; c < FRN; ++c)
                    acc[r][c] = __builtin_amdgcn_mfma_f32_16x16x32_bf16(
                        af[r], bfr[c], acc[r][c], 0, 0, 0);
            __builtin_amdgcn_s_setprio(0);
        }
        __builtin_amdgcn_sched_barrier(0);
        __builtin_amdgcn_s_barrier();        // all waves done reading buf[cur]
        __builtin_amdgcn_sched_barrier(0);
        if (t + 3 < steps) stage(cur, t + 3);   // overwrite now safe
        cur = (cur == 2) ? 0 : cur + 1;
    }

    // epilogue — C/D layout: col = lane&15, row = (lane>>4)*4 + q  [m89]
#pragma unroll
    for (int r = 0; r < FRM; ++r)
#pragma unroll
        for (int c = 0; c < FRN; ++c) {
            const size_t col = n0 + wc0 + c * 16 + lq;
#pragma unroll
            for (int q = 0; q < 4; ++q) {
                const size_t row = m0 + wr0 + r * 16 + kh * 4 + q;
                float v = acc[r][c][q];
                if constexpr (MODE == 0) {
                    v += e0[col] + e1[col];
                    ushort hb = f2bf(v);
                    ushort lb = f2bf(v - bf2f(hb));
                    shiO[row * ldn + col] = hb;
                    sloO[row * ldn + col] = lb;
                } else if constexpr (MODE == 1) {
                    v += bf2f(uA[row * ldn + col]) + bf2f(uB[row * ldn + col]);
                    if (flag != 0.f) v += flag * e1[col];
                    float s = tanhf(v);
                    ushort hb = f2bf(s);
                    ushort lb = f2bf(s - bf2f(hb));
                    shiO[row * ldn + col] = hb;
                    sloO[row * ldn + col] = lb;
                } else {                      // MODE 3
                    Cout[row * ldn + col] = v + e1[row] * e0[col];
                }
            }
        }
}

// 1-D grid + bijective XCD swizzle (requires gridDim.x % 8 == 0)
template<int BM, int BN, int MODE>
__global__ __launch_bounds__(256)
void mfma_gemm(int gx,
               const ushort* __restrict__ ahi, const ushort* __restrict__ alo, int lda,
               const ushort* __restrict__ bhi, const ushort* __restrict__ blo, int ldb,
               int tps, float* __restrict__ Cout, int ldn,
               const float* __restrict__ e0, const float* __restrict__ e1,
               float flag,
               const ushort* __restrict__ uA, const ushort* __restrict__ uB,
               ushort* __restrict__ shiO, ushort* __restrict__ sloO)
{
    __shared__ __align__(16) ushort smem[3 * (BM + BN) * 64];
    const int n = gridDim.x;
    const int b = blockIdx.x;
    const int w = (b & 7) * (n >> 3) + (b >> 3);   // same-XCD blocks contiguous
    gemm_body<BM, BN, MODE>(w % gx, w / gx, ahi, alo, lda, bhi, blo, ldb,
                            tps, Cout, ldn, e0, e1, flag, uA, uB,
                            shiO, sloO, smem);
}

// ---------------------------------------------------------------------------
__global__ void init_kernel(float* __restrict__ sacc_zero, size_t nzero,
                            float* __restrict__ hA, float* __restrict__ rA,
                            float* __restrict__ RA, float* __restrict__ NA,
                            float* __restrict__ stA, float* __restrict__ pAcc,
                            const float* __restrict__ prev_steps, int B)
{
    size_t i = (size_t)blockIdx.x * 256 + threadIdx.x;
    if (i < nzero) sacc_zero[i] = 0.f;
    if (i < (size_t)B) {
        hA[i] = 0.f; rA[i] = 1.f; RA[i] = 1.f; NA[i] = 0.f;
        stA[i] = prev_steps[i] + 1.f; pAcc[i] = 0.f;
    }
}

__global__ void split_f32(const float* __restrict__ src,
                          ushort* __restrict__ hi, ushort* __restrict__ lo, size_t n4)
{
    size_t i = (size_t)blockIdx.x * 256 + threadIdx.x;
    if (i < n4) {
        float4 v = reinterpret_cast<const float4*>(src)[i];
        ushort4 h, l;
        h.x = f2bf(v.x); l.x = f2bf(v.x - bf2f(h.x));
        h.y = f2bf(v.y); l.y = f2bf(v.y - bf2f(h.y));
        h.z = f2bf(v.z); l.z = f2bf(v.z - bf2f(h.z));
        h.w = f2bf(v.w); l.w = f2bf(v.w - bf2f(h.w));
        reinterpret_cast<ushort4*>(hi)[i] = h;
        reinterpret_cast<ushort4*>(lo)[i] = l;
    }
}

// W_ih[H, D+1] -> split [H,D] + wcol[H]
__global__ void wih_split(const float* __restrict__ Wih,
                          ushort* __restrict__ hi, ushort* __restrict__ lo,
                          float* __restrict__ wcol, int H, int D)
{
    size_t i = (size_t)blockIdx.x * 256 + threadIdx.x;
    if (i < (size_t)H * D) {
        int h = (int)(i / D), d = (int)(i % D);
        float v = Wih[(size_t)h * (D + 1) + d];
        ushort hb = f2bf(v);
        hi[i] = hb; lo[i] = f2bf(v - bf2f(hb));
    }
    if (i < (size_t)H) wcol[i] = Wih[i * (size_t)(D + 1) + D];
}

// per-row halt state machine; s_acc += p*s; P += p.
// isFinal: also writes split(s_acc_final) for the y-GEMM A-operand.
__global__ __launch_bounds__(256)
void halt_update(const ushort* __restrict__ shi, const ushort* __restrict__ slo,
                 const float* __restrict__ Whalt, const float* __restrict__ bhalt,
                 float* __restrict__ hA, float* __restrict__ rA, float* __restrict__ RA,
                 float* __restrict__ NA, float* __restrict__ stA,
                 float* __restrict__ pAcc,
                 float* __restrict__ s_acc,
                 ushort* __restrict__ fsHi, ushort* __restrict__ fsLo,
                 float n1, int H, int isFinal)
{
    const int b = blockIdx.x;
    const int tid = threadIdx.x;
    const size_t base = (size_t)b * H;
    const int i = tid * 4;                     // H == 1024 == 256*4
    ushort4 h4 = *reinterpret_cast<const ushort4*>(shi + base + i);
    ushort4 l4 = *reinterpret_cast<const ushort4*>(slo + base + i);
    float s0 = bf2f(h4.x) + bf2f(l4.x);
    float s1 = bf2f(h4.y) + bf2f(l4.y);
    float s2 = bf2f(h4.z) + bf2f(l4.z);
    float s3 = bf2f(h4.w) + bf2f(l4.w);

    __shared__ float partial[4];
    __shared__ float psh;
    float4 w4 = *reinterpret_cast<const float4*>(Whalt + i);
    float lsum = s0 * w4.x + s1 * w4.y + s2 * w4.z + s3 * w4.w;
#pragma unroll
    for (int off = 32; off > 0; off >>= 1) lsum += __shfl_down(lsum, off, 64);
    if ((tid & 63) == 0) partial[tid >> 6] = lsum;
    __syncthreads();
    if (tid == 0) {
        float pv;
        if (isFinal) {
            pv = rA[b];
        } else {
            float dot = partial[0] + partial[1] + partial[2] + partial[3] + bhalt[0];
            float h_n = 1.f / (1.f + expf(-dot));
            float hh = hA[b] + h_n;
            bool isN = hh >= 0.99f;            // 1 - EPS
            pv = isN ? rA[b] : h_n;
            float r_new = isN ? 0.f : 1.f - hh;
            if (!isN) { RA[b] = r_new; NA[b] = n1; stA[b] += 1.f; }
            hA[b] = hh; rA[b] = r_new;
        }
        pAcc[b] += pv;                         // P = sum of all p_n
        psh = pv;
    }
    __syncthreads();
    const float pv = psh;
    float4* sac = reinterpret_cast<float4*>(s_acc + base + i);
    if (!isFinal) {
        if (pv != 0.f) {
            float4 o = *sac;
            o.x = fmaf(pv, s0, o.x); o.y = fmaf(pv, s1, o.y);
            o.z = fmaf(pv, s2, o.z); o.w = fmaf(pv, s3, o.w);
            *sac = o;
        }
    } else {
        float4 o = *sac;                       // pv may be 0; fmaf identity
        o.x = fmaf(pv, s0, o.x); o.y = fmaf(pv, s1, o.y);
        o.z = fmaf(pv, s2, o.z); o.w = fmaf(pv, s3, o.w);
        *sac = o;
        ushort4 fh, fl;
        fh.x = f2bf(o.x); fl.x = f2bf(o.x - bf2f(fh.x));
        fh.y = f2bf(o.y); fl.y = f2bf(o.y - bf2f(fh.y));
        fh.z = f2bf(o.z); fl.z = f2bf(o.z - bf2f(fh.z));
        fh.w = f2bf(o.w); fl.w = f2bf(o.w - bf2f(fh.w));
        *reinterpret_cast<ushort4*>(fsHi + base + i) = fh;
        *reinterpret_cast<ushort4*>(fsLo + base + i) = fl;
    }
}

__global__ void finalize_kernel(const float* __restrict__ pp, const float* __restrict__ RA,
                                const float* __restrict__ NA, const float* __restrict__ stA,
                                float* __restrict__ pon, float* __restrict__ stp, int B)
{
    int i = blockIdx.x * 256 + threadIdx.x;
    if (i < B) { pon[i] = pp[i] + RA[i] + NA[i]; stp[i] = stA[i]; }
}

// ---------------------------------------------------------------------------
extern "C" void kernel_launch(void* const* d_in, const int* in_sizes, int n_in,
                              void* d_out, int out_size, void* d_ws, size_t ws_size,
                              hipStream_t stream)
{
    const float* x     = (const float*)d_in[0];
    const float* ph    = (const float*)d_in[1];
    const float* pp    = (const float*)d_in[2];
    const float* ps    = (const float*)d_in[3];
    const float* Wih   = (const float*)d_in[4];
    const float* bih   = (const float*)d_in[5];
    const float* Whh   = (const float*)d_in[6];
    const float* bhh   = (const float*)d_in[7];
    const float* Whalt = (const float*)d_in[8];
    const float* bhalt = (const float*)d_in[9];
    const float* Wans  = (const float*)d_in[10];
    const float* bans  = (const float*)d_in[11];

    const int B = in_sizes[2];
    const int H = in_sizes[5];
    const int O = in_sizes[11];
    const int D = in_sizes[0] / B;

    float* out_y   = (float*)d_out;
    float* out_sac = out_y + (size_t)B * O;
    float* out_pon = out_sac + (size_t)B * H;
    float* out_stp = out_pon + B;

    // workspace layout (16B-aligned chunks)
    char* w = (char*)d_ws;
    ushort* xpHi = (ushort*)w; w += (size_t)B * H * 2;
    ushort* xpLo = (ushort*)w; w += (size_t)B * H * 2;
    ushort* shi[2], *slo[2];
    shi[0] = (ushort*)w; w += (size_t)B * H * 2;
    slo[0] = (ushort*)w; w += (size_t)B * H * 2;
    shi[1] = (ushort*)w; w += (size_t)B * H * 2;
    slo[1] = (ushort*)w; w += (size_t)B * H * 2;
    ushort* whhhi = (ushort*)w; w += (size_t)H * H * 2;
    ushort* whhlo = (ushort*)w; w += (size_t)H * H * 2;
    ushort* wanshi = (ushort*)w; w += (size_t)O * H * 2;
    ushort* wanslo = (ushort*)w; w += (size_t)O * H * 2;
    ushort* wihhi = (ushort*)w; w += (size_t)H * D * 2;
    ushort* wihlo = (ushort*)w; w += (size_t)H * D * 2;
    float* wcol = (float*)w; w += (size_t)H * 4;
    float* hA   = (float*)w; w += (size_t)B * 4;
    float* rA   = (float*)w; w += (size_t)B * 4;
    float* RA   = (float*)w; w += (size_t)B * 4;
    float* NA   = (float*)w; w += (size_t)B * 4;
    float* stA  = (float*)w; w += (size_t)B * 4;
    float* pAcc = (float*)w; w += (size_t)B * 4;

    // x split aliases s[1] (dead before s[1] first written at t=0 MODE1);
    // s_acc split aliases xpHi/xpLo (xproj last read by MODE1 t=9, which
    // completes before the final halt writes these — stream-ordered).
    ushort* xhi = shi[1];
    ushort* xlo = slo[1];
    ushort* sacHi = xpHi;
    ushort* sacLo = xpLo;

    init_kernel<<<(unsigned)(((size_t)B * H + 255) / 256), 256, 0, stream>>>(
        out_sac, (size_t)B * H, hA, rA, RA, NA, stA, pAcc, ps, B);

    split_f32<<<(unsigned)(((size_t)B * D / 4 + 255) / 256), 256, 0, stream>>>(x, xhi, xlo, (size_t)B * D / 4);
    split_f32<<<(unsigned)(((size_t)B * H / 4 + 255) / 256), 256, 0, stream>>>(ph, shi[0], slo[0], (size_t)B * H / 4);
    split_f32<<<(unsigned)(((size_t)H * H / 4 + 255) / 256), 256, 0, stream>>>(Whh, whhhi, whhlo, (size_t)H * H / 4);
    split_f32<<<(unsigned)(((size_t)O * H / 4 + 255) / 256), 256, 0, stream>>>(Wans, wanshi, wanslo, (size_t)O * H / 4);
    wih_split<<<(unsigned)(((size_t)H * D + 255) / 256), 256, 0, stream>>>(Wih, wihhi, wihlo, wcol, H, D);

    // xproj = split(x @ W_ih[:, :D]^T + b_ih + b_hh)
    mfma_gemm<64, 128, 0><<<(B / 64) * (H / 128), 256, 0, stream>>>(
        B / 64, xhi, xlo, D, wihhi, wihlo, D, D / 64,
        nullptr, H, bih, bhh, 0.f, nullptr, nullptr, xpHi, xpLo);

    // step 0: MODE1 with flag=1
    mfma_gemm<64, 128, 1><<<(B / 64) * (H / 128), 256, 0, stream>>>(
        B / 64, shi[0], slo[0], H, whhhi, whhlo, H, H / 64,
        nullptr, H, nullptr, wcol, 1.f, xpHi, xpLo, shi[1], slo[1]);

    int cur = 1;   // s after step 0 lives in buffer 1
    for (int t = 1; t < MAX_ITER; t++) {
        // halt for step t-1 (uses s[cur]); n = (t-1)+2
        halt_update<<<B, 256, 0, stream>>>(
            shi[cur], slo[cur], Whalt, bhalt, hA, rA, RA, NA, stA, pAcc,
            out_sac, nullptr, nullptr, (float)(t + 1), H, 0);
        // MODE1(t): s[cur] -> s[cur^1]
        mfma_gemm<64, 128, 1><<<(B / 64) * (H / 128), 256, 0, stream>>>(
            B / 64, shi[cur], slo[cur], H, whhhi, whhlo, H, H / 64,
            nullptr, H, nullptr, wcol, 0.f, xpHi, xpLo, shi[cur ^ 1], slo[cur ^ 1]);
        cur ^= 1;
    }

    // final halt (step 9): p = r, s_acc += r*s, P += r, write split(s_acc)
    halt_update<<<B, 256, 0, stream>>>(
        shi[cur], slo[cur], Whalt, bhalt, hA, rA, RA, NA, stA, pAcc,
        out_sac, sacHi, sacLo, 0.f, H, 1);

    // y = s_acc @ Wans^T + P * b_ans   (single GEMM, full write)
    mfma_gemm<64, 64, 3><<<(B / 64) * (O / 64), 256, 0, stream>>>(
        B / 64, sacHi, sacLo, H, wanshi, wanslo, H, H / 64,
        out_y, O, bans, pAcc, 0.f, nullptr, nullptr, nullptr, nullptr);

    finalize_kernel<<<(B + 255) / 256, 256, 0, stream>>>(
        pp, RA, NA, stA, out_pon, out_stp, B);
}